// Round 6
// baseline (130.776 us; speedup 1.0000x reference)
//
#include <hip/hip_runtime.h>
#include <hip/hip_bf16.h>
#include <cstdint>
#include <cstddef>

typedef __attribute__((ext_vector_type(8))) short short8;
typedef __attribute__((ext_vector_type(4))) float f32x4;

static constexpr int M_TOT = 31744;
static constexpr int N_TOT = 1152;
static constexpr int K_TOT = 768;
static constexpr long A_ELEMS = (long)M_TOT * K_TOT;   // 24379392
static constexpr long W_ELEMS = (long)N_TOT * K_TOT;   // 884736
static constexpr int CYC_ROWS = 3968;                  // one ragged cycle (4 images)

__device__ __forceinline__ unsigned short f2bf(float f) {
  unsigned int u = __float_as_uint(f);
  u += 0x7FFFu + ((u >> 16) & 1u);   // round-to-nearest-even
  return (unsigned short)(u >> 16);
}
__device__ __forceinline__ float bf2f(unsigned short u) {
  return __uint_as_float((unsigned int)u << 16);
}

// ---------------- pass 1: fp32 -> bf16 for A (seq_patches) and W ----------------
__global__ void cvt_kernel(const float* __restrict__ A, const float* __restrict__ W,
                           unsigned short* __restrict__ dst) {
  long chunk = (long)blockIdx.x * blockDim.x + threadIdx.x;  // one chunk = 8 floats
  long i = chunk * 8;
  const float* src = (i < A_ELEMS) ? (A + i) : (W + (i - A_ELEMS));
  float4 v0 = *(const float4*)(src);
  float4 v1 = *(const float4*)(src + 4);
  short8 o;
  o[0] = (short)f2bf(v0.x); o[1] = (short)f2bf(v0.y);
  o[2] = (short)f2bf(v0.z); o[3] = (short)f2bf(v0.w);
  o[4] = (short)f2bf(v1.x); o[5] = (short)f2bf(v1.y);
  o[6] = (short)f2bf(v1.z); o[7] = (short)f2bf(v1.w);
  *(short8*)(dst + i) = o;
}

// ---------------- pass 1b: pos table  tab[rem,d] = bf16(bias[d] + bilinear(pos)[rem,d]) ----
__global__ void tab_kernel(const float* __restrict__ pos, const float* __restrict__ bias,
                           unsigned short* __restrict__ tab) {
  const int t = blockIdx.x * blockDim.x + threadIdx.x;   // 571392 = 3968 * 144
  const int row = t / 144;                                // rem in [0,3968)
  const int dc = (t - row * 144) * 8;                     // d chunk base

  int rr, cc; float sy, sx;
  if (row < 1024)      { rr = row >> 5; cc = row & 31; sy = 0.5f;         sx = 0.5f; }
  else if (row < 2048) { const int li = row - 1024; rr = li >> 6; cc = li & 63; sy = 1.0f; sx = 0.25f; }
  else if (row < 3008) { const int li = row - 2048; rr = li / 40; cc = li - rr * 40; sy = 16.0f / 24.0f; sx = 0.4f; }
  else                 { const int li = row - 3008; rr = li / 24; cc = li - rr * 24; sy = 0.4f; sx = 16.0f / 24.0f; }
  float yc = fminf(fmaxf(((float)rr + 0.5f) * sy - 0.5f, 0.0f), 15.0f);
  const int y0 = (int)yc; const float fy = yc - (float)y0;
  const int y1 = y0 < 15 ? y0 + 1 : 15;
  float xc = fminf(fmaxf(((float)cc + 0.5f) * sx - 0.5f, 0.0f), 15.0f);
  const int x0 = (int)xc; const float fx = xc - (float)x0;
  const int x1 = x0 < 15 ? x0 + 1 : 15;
  const float w11 = fy * fx;
  const float w10 = fy - w11;
  const float w01 = fx - w11;
  const float w00 = 1.0f - fy - fx + w11;
  const float* p00 = pos + (size_t)(y0 * 16 + x0) * 1152 + dc;
  const float* p01 = pos + (size_t)(y0 * 16 + x1) * 1152 + dc;
  const float* p10 = pos + (size_t)(y1 * 16 + x0) * 1152 + dc;
  const float* p11 = pos + (size_t)(y1 * 16 + x1) * 1152 + dc;
  const float* bi  = bias + dc;
  short8 o;
#pragma unroll
  for (int j = 0; j < 8; ++j) {
    const float v = bi[j] + w00 * p00[j] + w01 * p01[j] + w10 * p10[j] + w11 * p11[j];
    o[j] = (short)f2bf(v);
  }
  *(short8*)(tab + (size_t)row * 1152 + dc) = o;
}

__device__ __forceinline__ void gload_lds16(const void* g, void* l) {
  __builtin_amdgcn_global_load_lds((__attribute__((address_space(1))) void*)g,
                                   (__attribute__((address_space(3))) void*)l, 16, 0, 0);
}

// ---------------- pass 2: bf16 MFMA GEMM, 2-phase double-buffered, swapped-D ----
// 128x128 tile, BK=64, 256 threads = 4 waves (2x2), wave-tile 64x64.
// MFMA operands SWAPPED (mfma(fb, fa)) so D is transposed: each lane's 4 acc
// regs hold 4 consecutive d-columns of ONE output row -> epilogue stores are
// global_store_dwordx4 (16x fewer store instructions than scalar layout).
__global__ __launch_bounds__(256) void gemm_kernel(
    const unsigned short* __restrict__ Abf, const unsigned short* __restrict__ Wbf,
    const unsigned short* __restrict__ tab, float* __restrict__ outp) {
  __shared__ __attribute__((aligned(16))) unsigned short As[2][128 * 64];  // 2 x 16 KB
  __shared__ __attribute__((aligned(16))) unsigned short Bs[2][128 * 64];  // 2 x 16 KB

  // XCD-bijective swizzle: 2232 tiles = 8 XCDs * 279.  Same-M panels stay on one XCD.
  const int bid = blockIdx.x;
  const int tile = (bid & 7) * 279 + (bid >> 3);
  const int tm = tile / 9, tn = tile % 9;   // 248 x 9 tiles of 128x128
  const int m0 = tm * 128, n0 = tn * 128;

  const int tid = threadIdx.x;
  const int wid = tid >> 6, lane = tid & 63;
  const int wr = wid >> 1, wc = wid & 1;    // 2x2 waves, 64x64 each
  const int rb = wid * 32;                  // this wave's staging row base
  const int lrow = lane >> 3;               // 0..7 rows per 1KB wave-call
  const int lcol = ((lane & 7) ^ lrow) * 8; // pre-swizzled source chunk (elements)
  const int kg = lane >> 4, l15 = lane & 15;

  f32x4 acc[4][4] = {};

  const unsigned short* Abase = Abf + (size_t)m0 * K_TOT;
  const unsigned short* Bbase = Wbf + (size_t)n0 * K_TOT;

#define STAGE(p, kt)                                                             \
  { const int k0_ = (kt) * 64;                                                   \
    _Pragma("unroll") for (int c = 0; c < 4; ++c) {                              \
      const int row_ = rb + c * 8;                                               \
      gload_lds16(Abase + (size_t)(row_ + lrow) * K_TOT + k0_ + lcol,            \
                  (char*)As[p] + row_ * 128);                                    \
      gload_lds16(Bbase + (size_t)(row_ + lrow) * K_TOT + k0_ + lcol,            \
                  (char*)Bs[p] + row_ * 128);                                    \
    } }

#define COMPUTE(p)                                                               \
  { __builtin_amdgcn_s_setprio(1);                                               \
    _Pragma("unroll") for (int kk = 0; kk < 2; ++kk) {                           \
      short8 fa[4], fb[4];                                                       \
      _Pragma("unroll") for (int m = 0; m < 4; ++m) {                            \
        const int arow = wr * 64 + m * 16 + l15;                                 \
        fa[m] = *(const short8*)((const char*)As[p] + arow * 128 +               \
                                 (((kk * 4 + kg) ^ (arow & 7)) << 4));           \
      }                                                                          \
      _Pragma("unroll") for (int n = 0; n < 4; ++n) {                            \
        const int brow = wc * 64 + n * 16 + l15;                                 \
        fb[n] = *(const short8*)((const char*)Bs[p] + brow * 128 +               \
                                 (((kk * 4 + kg) ^ (brow & 7)) << 4));           \
      }                                                                          \
      /* swapped operands: D row-dim <-> W-col (d), D col-dim <-> A-row (s) */   \
      _Pragma("unroll") for (int m = 0; m < 4; ++m)                              \
        _Pragma("unroll") for (int n = 0; n < 4; ++n)                            \
          acc[m][n] = __builtin_amdgcn_mfma_f32_16x16x32_bf16(                   \
              fb[n], fa[m], acc[m][n], 0, 0, 0);                                 \
    }                                                                            \
    __builtin_amdgcn_s_setprio(0); }

  // prologue: stage tile 0, full drain, barrier
  STAGE(0, 0)
  asm volatile("s_waitcnt vmcnt(0)" ::: "memory");
  __builtin_amdgcn_s_barrier();

  // main loop: stage t+1 into q BEFORE computing p; one drain+barrier per tile.
#pragma unroll
  for (int t = 0; t < 11; ++t) {
    const int p = t & 1, q = p ^ 1;
    STAGE(q, t + 1)
    COMPUTE(p)
    asm volatile("s_waitcnt vmcnt(0)" ::: "memory");
    __builtin_amdgcn_s_barrier();
  }
  COMPUTE(1)   // tile 11 resides in buf 1

#undef STAGE
#undef COMPUTE

  // ---------------- epilogue: out = acc + tab[s % 3968, d], vectorized ----------
  // swapped-D layout: s = m0 + wr*64 + m*16 + (lane&15)
  //                   d = n0 + wc*64 + n*16 + (lane>>4)*4 + r   (r = acc reg)
  const int s_row0 = m0 + wr * 64 + l15;
  const int rem_b  = s_row0 % CYC_ROWS;
  const int d0     = n0 + wc * 64 + (lane >> 4) * 4;

#pragma unroll
  for (int m = 0; m < 4; ++m) {
    int rem = rem_b + m * 16;
    if (rem >= CYC_ROWS) rem -= CYC_ROWS;
    const unsigned short* trow = tab + (size_t)rem * 1152 + d0;
    float* orow = outp + (size_t)(s_row0 + m * 16) * 1152 + d0;
#pragma unroll
    for (int n = 0; n < 4; ++n) {
      const ushort4 t4 = *(const ushort4*)(trow + n * 16);
      f32x4 v;
      v[0] = acc[m][n][0] + bf2f(t4.x);
      v[1] = acc[m][n][1] + bf2f(t4.y);
      v[2] = acc[m][n][2] + bf2f(t4.z);
      v[3] = acc[m][n][3] + bf2f(t4.w);
      *(f32x4*)(orow + n * 16) = v;
    }
  }
}

extern "C" void kernel_launch(void* const* d_in, const int* in_sizes, int n_in,
                              void* d_out, int out_size, void* d_ws, size_t ws_size,
                              hipStream_t stream) {
  const float* A    = (const float*)d_in[0];  // seq_patches [31744,768]
  const float* W    = (const float*)d_in[1];  // w [1152,768]
  const float* bias = (const float*)d_in[2];  // b [1152]
  const float* pos  = (const float*)d_in[3];  // pos_emb [256,1152]
  unsigned short* Abf = (unsigned short*)d_ws;            // 48.76 MB
  unsigned short* Wbf = Abf + A_ELEMS;                    // +1.77 MB
  unsigned short* tab = Wbf + W_ELEMS;                    // +9.14 MB (3968*1152)
  float* outp = (float*)d_out;

  cvt_kernel<<<12336, 256, 0, stream>>>(A, W, Abf);
  tab_kernel<<<2232, 256, 0, stream>>>(pos, bias, tab);
  gemm_kernel<<<2232, 256, 0, stream>>>(Abf, Wbf, tab, outp);
}

// Round 7
// 116.979 us; speedup vs baseline: 1.1179x; 1.1179x over previous
//
#include <hip/hip_runtime.h>
#include <hip/hip_bf16.h>
#include <cstdint>
#include <cstddef>

typedef __attribute__((ext_vector_type(8))) short short8;
typedef __attribute__((ext_vector_type(4))) float f32x4;

static constexpr int M_TOT = 31744;
static constexpr int N_TOT = 1152;
static constexpr int K_TOT = 768;
static constexpr long A_ELEMS = (long)M_TOT * K_TOT;   // 24379392
static constexpr long W_ELEMS = (long)N_TOT * K_TOT;   // 884736
static constexpr int CYC_ROWS = 3968;                  // one ragged cycle (4 images)

__device__ __forceinline__ unsigned short f2bf(float f) {
  unsigned int u = __float_as_uint(f);
  u += 0x7FFFu + ((u >> 16) & 1u);   // round-to-nearest-even
  return (unsigned short)(u >> 16);
}
__device__ __forceinline__ float bf2f(unsigned short u) {
  return __uint_as_float((unsigned int)u << 16);
}

// ---------------- pass 1: fp32 -> bf16 for A (seq_patches) and W ----------------
__global__ void cvt_kernel(const float* __restrict__ A, const float* __restrict__ W,
                           unsigned short* __restrict__ dst) {
  long chunk = (long)blockIdx.x * blockDim.x + threadIdx.x;  // one chunk = 8 floats
  long i = chunk * 8;
  const float* src = (i < A_ELEMS) ? (A + i) : (W + (i - A_ELEMS));
  float4 v0 = *(const float4*)(src);
  float4 v1 = *(const float4*)(src + 4);
  short8 o;
  o[0] = (short)f2bf(v0.x); o[1] = (short)f2bf(v0.y);
  o[2] = (short)f2bf(v0.z); o[3] = (short)f2bf(v0.w);
  o[4] = (short)f2bf(v1.x); o[5] = (short)f2bf(v1.y);
  o[6] = (short)f2bf(v1.z); o[7] = (short)f2bf(v1.w);
  *(short8*)(dst + i) = o;
}

// ---------------- pass 1b: pos table  tab[rem,d] = bf16(bias[d] + bilinear(pos)[rem,d]) ----
__global__ void tab_kernel(const float* __restrict__ pos, const float* __restrict__ bias,
                           unsigned short* __restrict__ tab) {
  const int t = blockIdx.x * blockDim.x + threadIdx.x;   // 571392 = 3968 * 144
  const int row = t / 144;                                // rem in [0,3968)
  const int dc = (t - row * 144) * 8;                     // d chunk base

  int rr, cc; float sy, sx;
  if (row < 1024)      { rr = row >> 5; cc = row & 31; sy = 0.5f;         sx = 0.5f; }
  else if (row < 2048) { const int li = row - 1024; rr = li >> 6; cc = li & 63; sy = 1.0f; sx = 0.25f; }
  else if (row < 3008) { const int li = row - 2048; rr = li / 40; cc = li - rr * 40; sy = 16.0f / 24.0f; sx = 0.4f; }
  else                 { const int li = row - 3008; rr = li / 24; cc = li - rr * 24; sy = 0.4f; sx = 16.0f / 24.0f; }
  float yc = fminf(fmaxf(((float)rr + 0.5f) * sy - 0.5f, 0.0f), 15.0f);
  const int y0 = (int)yc; const float fy = yc - (float)y0;
  const int y1 = y0 < 15 ? y0 + 1 : 15;
  float xc = fminf(fmaxf(((float)cc + 0.5f) * sx - 0.5f, 0.0f), 15.0f);
  const int x0 = (int)xc; const float fx = xc - (float)x0;
  const int x1 = x0 < 15 ? x0 + 1 : 15;
  const float w11 = fy * fx;
  const float w10 = fy - w11;
  const float w01 = fx - w11;
  const float w00 = 1.0f - fy - fx + w11;
  const float* p00 = pos + (size_t)(y0 * 16 + x0) * 1152 + dc;
  const float* p01 = pos + (size_t)(y0 * 16 + x1) * 1152 + dc;
  const float* p10 = pos + (size_t)(y1 * 16 + x0) * 1152 + dc;
  const float* p11 = pos + (size_t)(y1 * 16 + x1) * 1152 + dc;
  const float* bi  = bias + dc;
  short8 o;
#pragma unroll
  for (int j = 0; j < 8; ++j) {
    const float v = bi[j] + w00 * p00[j] + w01 * p01[j] + w10 * p10[j] + w11 * p11[j];
    o[j] = (short)f2bf(v);
  }
  *(short8*)(tab + (size_t)row * 1152 + dc) = o;
}

__device__ __forceinline__ void gload_lds16(const void* g, void* l) {
  __builtin_amdgcn_global_load_lds((__attribute__((address_space(1))) void*)g,
                                   (__attribute__((address_space(3))) void*)l, 16, 0, 0);
}

// ---------------- pass 2: bf16 MFMA GEMM, BK=32 triple-buffer, 2-deep prefetch ----
// 128x128 tile, 256 threads = 4 waves (2x2), wave-tile 64x64, 24 K-steps.
// LDS 3 x (A 8KB + B 8KB) = 48 KB -> 3 blocks/CU, AND tile t's loads issued at
// iter t-2 -> ~2 compute periods of latency cover. Counted vmcnt(8) guard —
// never drains to 0 until the tail. Rows are 64 B; XOR key (row>>1)&3 on 16-B
// chunks gives exact 2-way bank aliasing (free, m136).
__global__ __launch_bounds__(256) void gemm_kernel(
    const unsigned short* __restrict__ Abf, const unsigned short* __restrict__ Wbf,
    const unsigned short* __restrict__ tab, float* __restrict__ outp) {
  __shared__ __attribute__((aligned(16))) unsigned short As[3][128 * 32];  // 3 x 8 KB
  __shared__ __attribute__((aligned(16))) unsigned short Bs[3][128 * 32];  // 3 x 8 KB

  // XCD-bijective swizzle: 2232 tiles = 8 XCDs * 279.
  const int bid = blockIdx.x;
  const int tile = (bid & 7) * 279 + (bid >> 3);
  const int tm = tile / 9, tn = tile % 9;   // 248 x 9 tiles of 128x128
  const int m0 = tm * 128, n0 = tn * 128;

  const int tid = threadIdx.x;
  const int wid = tid >> 6, lane = tid & 63;
  const int wr = wid >> 1, wc = wid & 1;    // 2x2 waves, 64x64 each
  const int kg = lane >> 4, l15 = lane & 15;

  // staging: per call a wave covers 16 rows x 32 k (1 KB). lane -> row lane>>2,
  // 16B chunk (lane&3), pre-swizzled by key (row>>1)&3 = (lane>>3)&3.
  const int srow = lane >> 2;
  const int schunk = ((lane & 3) ^ ((lane >> 3) & 3)) * 8;   // element offset
  const unsigned short* Abase = Abf + (size_t)(m0 + wid * 16 + srow) * K_TOT + schunk;
  const unsigned short* Bbase = Wbf + (size_t)(n0 + wid * 16 + srow) * K_TOT + schunk;
  const int wu = wid << 10;                  // wave-uniform LDS byte base

  // ds_read swizzle key: arow = wr*64 + m*16 + l15 -> (arow>>1)&3 = (l15>>1)&3
  const int rkey = (l15 >> 1) & 3;

  f32x4 acc[4][4] = {};

#define STAGE(p, kt)                                                             \
  { const int k0_ = (kt) * 32;                                                   \
    gload_lds16(Abase + k0_,                      (char*)As[p] + wu);            \
    gload_lds16(Abase + (size_t)64 * K_TOT + k0_, (char*)As[p] + 4096 + wu);     \
    gload_lds16(Bbase + k0_,                      (char*)Bs[p] + wu);            \
    gload_lds16(Bbase + (size_t)64 * K_TOT + k0_, (char*)Bs[p] + 4096 + wu); }

#define COMPUTE(p)                                                               \
  { __builtin_amdgcn_s_setprio(1);                                               \
    short8 fa[4], fb[4];                                                         \
    _Pragma("unroll") for (int m = 0; m < 4; ++m) {                              \
      const int arow = wr * 64 + m * 16 + l15;                                   \
      fa[m] = *(const short8*)((const char*)As[p] + arow * 64 +                  \
                               ((kg ^ rkey) << 4));                              \
    }                                                                            \
    _Pragma("unroll") for (int n = 0; n < 4; ++n) {                              \
      const int brow = wc * 64 + n * 16 + l15;                                   \
      fb[n] = *(const short8*)((const char*)Bs[p] + brow * 64 +                  \
                               ((kg ^ rkey) << 4));                              \
    }                                                                            \
    _Pragma("unroll") for (int m = 0; m < 4; ++m)                                \
      _Pragma("unroll") for (int n = 0; n < 4; ++n)                              \
        acc[m][n] = __builtin_amdgcn_mfma_f32_16x16x32_bf16(                     \
            fa[m], fb[n], acc[m][n], 0, 0, 0);                                   \
    __builtin_amdgcn_s_setprio(0); }

  // prologue: stage tiles 0 and 1 (8 loads in flight)
  STAGE(0, 0)
  STAGE(1, 1)

#pragma unroll
  for (int t = 0; t < 24; ++t) {
    const int p = t % 3;
    if (t + 2 < 24) {
      STAGE((t + 2) % 3, t + 2)   // in-flight: t(4) t+1(4) t+2(4)
      asm volatile("s_waitcnt vmcnt(8)" ::: "memory");   // drain tile t only
    } else if (t + 1 < 24) {
      asm volatile("s_waitcnt vmcnt(4)" ::: "memory");
    } else {
      asm volatile("s_waitcnt vmcnt(0)" ::: "memory");
    }
    __builtin_amdgcn_s_barrier();   // tile t fully resident for all waves
    COMPUTE(p)
    __builtin_amdgcn_s_barrier();   // nobody re-stages buf p until all read it
  }

#undef STAGE
#undef COMPUTE

  // ---------------- epilogue (round-5 layout): out = acc + tab[s % 3968, d] ----
  const int s_base = m0 + wr * 64 + ((lane >> 4) << 2);  // + m*16 + r
  const int rem_base = s_base % CYC_ROWS;                // one div per thread
  const int d_base = n0 + wc * 64 + l15;                 // + n*16

#pragma unroll
  for (int m = 0; m < 4; ++m) {
#pragma unroll
    for (int r = 0; r < 4; ++r) {
      const int off = m * 16 + r;
      int rem = rem_base + off;
      if (rem >= CYC_ROWS) rem -= CYC_ROWS;
      const unsigned short* trow = tab + (size_t)rem * 1152 + d_base;
      float* orow = outp + (size_t)(s_base + off) * 1152 + d_base;
#pragma unroll
      for (int n = 0; n < 4; ++n)
        orow[n * 16] = acc[m][n][r] + bf2f(trow[n * 16]);
    }
  }
}

extern "C" void kernel_launch(void* const* d_in, const int* in_sizes, int n_in,
                              void* d_out, int out_size, void* d_ws, size_t ws_size,
                              hipStream_t stream) {
  const float* A    = (const float*)d_in[0];  // seq_patches [31744,768]
  const float* W    = (const float*)d_in[1];  // w [1152,768]
  const float* bias = (const float*)d_in[2];  // b [1152]
  const float* pos  = (const float*)d_in[3];  // pos_emb [256,1152]
  unsigned short* Abf = (unsigned short*)d_ws;            // 48.76 MB
  unsigned short* Wbf = Abf + A_ELEMS;                    // +1.77 MB
  unsigned short* tab = Wbf + W_ELEMS;                    // +9.14 MB (3968*1152)
  float* outp = (float*)d_out;

  cvt_kernel<<<12336, 256, 0, stream>>>(A, W, Abf);
  tab_kernel<<<2232, 256, 0, stream>>>(pos, bias, tab);
  gemm_kernel<<<2232, 256, 0, stream>>>(Abf, Wbf, tab, outp);
}